// Round 16
// baseline (374.300 us; speedup 1.0000x reference)
//
#include <hip/hip_runtime.h>
#include <hip/hip_bf16.h>
#include <math.h>

#define NCOL 192   // 64 root | 64 rel0 | 64 rel1
#define BB   30    // bases
#define SCAN_T 256
#define SCAN_ELEMS 1024   // per scan block (4 per thread)

typedef short bf16x8 __attribute__((ext_vector_type(8)));
typedef float f32x4  __attribute__((ext_vector_type(4)));
typedef unsigned short u16x8 __attribute__((ext_vector_type(8)));

__device__ __forceinline__ ushort f2bf(float f) {
  unsigned u = __float_as_uint(f);
  unsigned r = u + 0x7fff + ((u >> 16) & 1);   // RTNE
  return (ushort)(r >> 16);
}
__device__ __forceinline__ float bf2f(ushort u) {
  return __uint_as_float(((unsigned)u) << 16);
}

// ---------------- CSR build ----------------
__global__ void zero_int(int* __restrict__ p, int n) {
  int i = blockIdx.x * blockDim.x + threadIdx.x;
  if (i < n) p[i] = 0;
}

__global__ void hist_deg(const int* __restrict__ dst, int* __restrict__ deg, int E) {
  int e = blockIdx.x * blockDim.x + threadIdx.x;
  if (e >= E) return;
  atomicAdd(&deg[dst[e]], 1);
}

__global__ __launch_bounds__(SCAN_T) void scan_local(const int* __restrict__ deg,
                                                     int* __restrict__ rowptr,
                                                     int* __restrict__ partial, int N) {
  __shared__ int sdata[SCAN_T];
  int t = threadIdx.x;
  int base = blockIdx.x * SCAN_ELEMS + t * 4;
  int v[4], s = 0;
#pragma unroll
  for (int k = 0; k < 4; ++k) {
    v[k] = (base + k < N) ? deg[base + k] : 0;
    s += v[k];
  }
  sdata[t] = s;
  __syncthreads();
  for (int off = 1; off < SCAN_T; off <<= 1) {
    int add = (t >= off) ? sdata[t - off] : 0;
    __syncthreads();
    sdata[t] += add;
    __syncthreads();
  }
  int run = sdata[t] - s;
  if (t == SCAN_T - 1) partial[blockIdx.x] = sdata[t];
#pragma unroll
  for (int k = 0; k < 4; ++k) {
    if (base + k <= N) rowptr[base + k] = run;   // includes index N
    run += v[k];
  }
}

__global__ __launch_bounds__(SCAN_T) void scan_partial(int* __restrict__ partial, int nb) {
  __shared__ int sdata[SCAN_T];
  int t = threadIdx.x;
  int v = (t < nb) ? partial[t] : 0;
  sdata[t] = v;
  __syncthreads();
  for (int off = 1; off < SCAN_T; off <<= 1) {
    int add = (t >= off) ? sdata[t - off] : 0;
    __syncthreads();
    sdata[t] += add;
    __syncthreads();
  }
  if (t < nb) partial[t] = sdata[t] - v;
  if (t == nb - 1) partial[nb] = sdata[t];
}

__global__ void scatter_edges(const int* __restrict__ src, const int* __restrict__ dst,
                              const int* __restrict__ et, const int* __restrict__ rowptr,
                              const int* __restrict__ partial,
                              int* __restrict__ fill, int* __restrict__ srcpk, int E) {
  int e = blockIdx.x * blockDim.x + threadIdx.x;
  if (e >= E) return;
  int d = dst[e];
  int pos = rowptr[d] + partial[d >> 10] + atomicAdd(&fill[d], 1);
  srcpk[pos] = src[e] | (et[e] << 30);
}

// ---------------- weights ----------------
// Wpk1: chunked + XOR-preswizzled: k -> chunk=k>>6, kg=(k>>3)&7, elem=k&7;
// slot=(kg*192+j)^kg; Wpk[chunk*12288 + slot*8 + elem].
// w2g/cb: WAVE per output c, lanes coalesced over o, shfl reduce.
__global__ void build_weights(const float* __restrict__ basis1, const float* __restrict__ comp1,
                              const float* __restrict__ root1,
                              const float* __restrict__ basis2, const float* __restrict__ comp2,
                              const float* __restrict__ root2,
                              const float* __restrict__ bias2, const float* __restrict__ gw,
                              ushort* __restrict__ Wpk1, float* __restrict__ w2g,
                              float* __restrict__ cb) {
  int idx = blockIdx.x * blockDim.x + threadIdx.x;
  if (idx < 512 * NCOL) {
    int k = idx / NCOL, j = idx - k * NCOL;
    float v;
    if (j < 64) {
      v = root1[k * 64 + j];
    } else {
      int r = (j >> 6) - 1, o = j & 63;
      float s = 0.f;
#pragma unroll
      for (int b = 0; b < BB; ++b)
        s = fmaf(comp1[r * BB + b], basis1[((size_t)b * 512 + k) * 64 + o], s);
      v = s;
    }
    int chunk = k >> 6, kg = (k >> 3) & 7, elem = k & 7;
    int slot = (kg * NCOL + j) ^ kg;
    Wpk1[(size_t)chunk * 12288 + slot * 8 + elem] = f2bf(v);
    return;
  }
  int widx = idx - 512 * NCOL;
  int c = widx >> 6;            // wave-aligned (base is 256-divisible)
  int o = widx & 63;
  if (c < 192) {
    int k = c & 63, part = c >> 6;
    float s;
    if (part == 0) {
      s = root2[k * 64 + o] * gw[o];
    } else {
      int r = part - 1;
      float t = 0.f;
#pragma unroll
      for (int b = 0; b < BB; ++b)
        t = fmaf(comp2[r * BB + b], basis2[((size_t)b * 64 + k) * 64 + o], t);
      s = t * gw[o];
    }
#pragma unroll
    for (int off = 32; off > 0; off >>= 1) s += __shfl_xor(s, off);
    if (o == 0) w2g[c] = s;
  } else if (c == 192) {
    float s = bias2[o] * gw[o];
#pragma unroll
    for (int off = 32; off > 0; off >>= 1) s += __shfl_xor(s, off);
    if (o == 0) *cb = s;
  }
}

// ---------------- GEMM: W -> LDS via async global_load_lds, A direct from global ----
// Per BK=64 chunk: W-chunk (24.6 KB) DMA'd straight to LDS (no VGPR round-trip,
// wave-uniform dest + lane*16; Wpk is pre-swizzled so the copy is linear).
// Issued into the idle buffer at top of chunk; ONE barrier per chunk.
// A: 2-chunk-deep register prefetch straight from global (16 rows x 128B).
template <int K, int BF16IN>
__global__ __launch_bounds__(256, 3) void gemm_mfma(const void* __restrict__ Xv,
                                                    const ushort* __restrict__ Wpk,
                                                    ushort* __restrict__ Y, int N) {
  constexpr int NC = K / 64;             // BK=64 chunks
  constexpr int NB = (NC > 1) ? 2 : 1;   // LDS buffers
  __shared__ ushort Ws[NB * 12288];      // 24.6 KB per buffer

  const int tid  = threadIdx.x;
  const int wid  = tid >> 6;
  const int lane = tid & 63;
  const int lrow = lane & 15;
  const int lhi  = lane >> 4;
  const int row0 = blockIdx.x * 64 + wid * 16;

  int lr = row0 + lrow;
  if (lr >= N) lr = N - 1;               // clamp A loads; C stores guarded
  const float*  Xf = (const float*)Xv  + (size_t)lr * K;
  const ushort* Xh = (const ushort*)Xv + (size_t)lr * K;

  // async W staging: wave w DMAs its 6144B segment, 6 x 1KB instructions.
  // LDS dest = wave-uniform base (HW adds lane*16); global src = per-lane.
#define GLOAD_W(c, buf)                                                        \
  { const ushort* gsrc = Wpk + (size_t)(c) * 12288 + wid * 3072 + lane * 8;    \
    ushort* ldst = Ws + (size_t)(buf) * 12288 + wid * 3072;                    \
    _Pragma("unroll") for (int i = 0; i < 6; ++i)                              \
      __builtin_amdgcn_global_load_lds(                                        \
          (const __attribute__((address_space(1))) unsigned int*)(gsrc + i * 512), \
          (__attribute__((address_space(3))) unsigned int*)(ldst + i * 512),   \
          16, 0, 0); }

  float4 pa[2][4];
  u16x8  ph[2][2];
#define LOAD_A(c, slot)                                                       \
  if constexpr (BF16IN) {                                                     \
    ph[slot][0] = ((const u16x8*)Xh)[(c) * 8 + lhi];                          \
    ph[slot][1] = ((const u16x8*)Xh)[(c) * 8 + 4 + lhi];                      \
  } else {                                                                    \
    _Pragma("unroll") for (int q = 0; q < 4; ++q)                             \
      pa[slot][q] = ((const float4*)Xf)[(c) * 16 + (q >> 1) * 8 + lhi * 2 + (q & 1)]; \
  }
#define MAT_A(slot, tt, areg)                                                 \
  if constexpr (BF16IN) {                                                     \
    areg = (bf16x8)ph[slot][tt];                                              \
  } else {                                                                    \
    float4 v0 = pa[slot][(tt) * 2], v1 = pa[slot][(tt) * 2 + 1];              \
    areg[0] = (short)f2bf(v0.x); areg[1] = (short)f2bf(v0.y);                 \
    areg[2] = (short)f2bf(v0.z); areg[3] = (short)f2bf(v0.w);                 \
    areg[4] = (short)f2bf(v1.x); areg[5] = (short)f2bf(v1.y);                 \
    areg[6] = (short)f2bf(v1.z); areg[7] = (short)f2bf(v1.w);                 \
  }
#define COMP(buf, tt, areg)                                                   \
  { const int kg = (tt) * 4 + lhi;                                            \
    const ushort* ls = Ws + (size_t)(buf) * 12288;                            \
    _Pragma("unroll") for (int h = 0; h < 2; ++h) {                           \
      bf16x8 b[6];                                                            \
      _Pragma("unroll") for (int q = 0; q < 6; ++q) {                         \
        int slot = (kg * NCOL + (h * 6 + q) * 16 + lrow) ^ (kg & 7);          \
        b[q] = *(const bf16x8*)(ls + slot * 8);                               \
      }                                                                       \
      _Pragma("unroll") for (int q = 0; q < 6; ++q)                           \
        acc[h * 6 + q] = __builtin_amdgcn_mfma_f32_16x16x32_bf16(areg, b[q],  \
                                                     acc[h * 6 + q], 0, 0, 0); \
    } }

  // prologue: DMA chunk 0, prefetch A chunks 0,1; barrier drains the DMA.
  GLOAD_W(0, 0)
  LOAD_A(0, 0)
  if constexpr (NC > 1) { LOAD_A(1, 1) }
  __syncthreads();

  f32x4 acc[12];
#pragma unroll
  for (int cc = 0; cc < 12; ++cc) acc[cc] = (f32x4){0.f, 0.f, 0.f, 0.f};

#pragma unroll
  for (int c = 0; c < NC; ++c) {
    // DMA next W chunk into the idle buffer (its last reader finished before
    // the previous barrier) -- lands during this chunk's MFMAs.
    if (c + 1 < NC) { GLOAD_W(c + 1, (c + 1) & 1) }
    bf16x8 a0, a1;
    MAT_A(c & 1, 0, a0)
    MAT_A(c & 1, 1, a1)
    if (c + 2 < NC) { LOAD_A(c + 2, c & 1) }
    COMP(NB > 1 ? (c & 1) : 0, 0, a0)
    COMP(NB > 1 ? (c & 1) : 0, 1, a1)
    if (c + 1 < NC) {
      __syncthreads();   // one barrier per chunk: drains DMA + readers
    }
  }
#undef GLOAD_W
#undef LOAD_A
#undef MAT_A
#undef COMP

  // C/D: col = lane&15, row = (lane>>4)*4 + reg   [m89]
#pragma unroll
  for (int cc = 0; cc < 12; ++cc) {
#pragma unroll
    for (int j = 0; j < 4; ++j) {
      int r = row0 + lhi * 4 + j;
      if (r < N) Y[(size_t)r * NCOL + cc * 16 + lrow] = f2bf(acc[cc][j]);
    }
  }
}

// ---------------- layer-1 aggregation (16 edges in flight per wave) ----------------
__global__ __launch_bounds__(256) void agg_layer1(const ushort* __restrict__ Y,
                                                  const int* __restrict__ rowptr,
                                                  const int* __restrict__ partial,
                                                  const int* __restrict__ srcpk,
                                                  const float* __restrict__ bias,
                                                  ushort* __restrict__ h1, int N) {
  int n = blockIdx.x * 4 + (threadIdx.x >> 6);
  if (n >= N) return;
  const int lane = threadIdx.x & 63;
  const int g    = lane >> 3;
  const int f0   = (lane & 7) * 8;

  float a0[8], a1[8];
#pragma unroll
  for (int j = 0; j < 8; ++j) { a0[j] = 0.f; a1[j] = 0.f; }
  float c0 = 0.f, c1 = 0.f;

  const int beg = rowptr[n] + partial[n >> 10];
  const int end = rowptr[n + 1] + partial[(n + 1) >> 10];
  for (int i = beg; i < end; i += 16) {
    int eA = i + g, eB = i + 8 + g;
    bool vA = eA < end, vB = eB < end;
    int pkA = 0, pkB = 0;
    if (vA) pkA = srcpk[eA];
    if (vB) pkB = srcpk[eB];
    u16x8 xA = (u16x8){0, 0, 0, 0, 0, 0, 0, 0}, xB = xA;
    if (vA) xA = *(const u16x8*)(Y + (size_t)(pkA & 0x3fffffff) * NCOL + 64 +
                                 ((pkA >> 30) << 6) + f0);
    if (vB) xB = *(const u16x8*)(Y + (size_t)(pkB & 0x3fffffff) * NCOL + 64 +
                                 ((pkB >> 30) << 6) + f0);
    float rA = (vA && (pkA >> 30)) ? 1.f : 0.f;
    float sA = vA ? 1.f : 0.f;
    float rB = (vB && (pkB >> 30)) ? 1.f : 0.f;
    float sB = vB ? 1.f : 0.f;
    c0 += (sA - rA) + (sB - rB);
    c1 += rA + rB;
#pragma unroll
    for (int j = 0; j < 8; ++j) {
      float fA = bf2f(xA[j]), fB = bf2f(xB[j]);
      a0[j] += (sA - rA) * fA + (sB - rB) * fB;
      a1[j] += rA * fA + rB * fB;
    }
  }

#pragma unroll
  for (int msk = 8; msk <= 32; msk <<= 1) {
#pragma unroll
    for (int j = 0; j < 8; ++j) {
      a0[j] += __shfl_xor(a0[j], msk);
      a1[j] += __shfl_xor(a1[j], msk);
    }
    c0 += __shfl_xor(c0, msk);
    c1 += __shfl_xor(c1, msk);
  }

  if (g == 0) {
    float inv0 = 1.f / fmaxf(c0, 1.f);
    float inv1 = 1.f / fmaxf(c1, 1.f);
    u16x8 rv = *(const u16x8*)(Y + (size_t)n * NCOL + f0);
    float4 bA = *(const float4*)(bias + f0);
    float4 bB = *(const float4*)(bias + f0 + 4);
    float bb[8] = {bA.x, bA.y, bA.z, bA.w, bB.x, bB.y, bB.z, bB.w};
    u16x8 o;
#pragma unroll
    for (int j = 0; j < 8; ++j) {
      float v = bf2f(rv[j]) + bb[j] + a0[j] * inv0 + a1[j] * inv1;
      o[j] = f2bf(fmaxf(v, 0.f));
    }
    *(u16x8*)(h1 + (size_t)n * 64 + f0) = o;
  }
}

// ---------------- layer-2 aggregation + folded GEMM (w2g dot) ----------------
__global__ __launch_bounds__(256) void agg_layer2(const ushort* __restrict__ h1,
                                                  const int* __restrict__ rowptr,
                                                  const int* __restrict__ partial,
                                                  const int* __restrict__ srcpk,
                                                  const float* __restrict__ w2g,
                                                  const float* __restrict__ cb,
                                                  float* __restrict__ hval, int N) {
  int n = blockIdx.x * 4 + (threadIdx.x >> 6);
  if (n >= N) return;
  const int lane = threadIdx.x & 63;
  const int g    = lane >> 3;
  const int f0   = (lane & 7) * 8;

  float a0[8], a1[8];
#pragma unroll
  for (int j = 0; j < 8; ++j) { a0[j] = 0.f; a1[j] = 0.f; }
  float c0 = 0.f, c1 = 0.f;

  const int beg = rowptr[n] + partial[n >> 10];
  const int end = rowptr[n + 1] + partial[(n + 1) >> 10];
  for (int i = beg; i < end; i += 16) {
    int eA = i + g, eB = i + 8 + g;
    bool vA = eA < end, vB = eB < end;
    int pkA = 0, pkB = 0;
    if (vA) pkA = srcpk[eA];
    if (vB) pkB = srcpk[eB];
    u16x8 xA = (u16x8){0, 0, 0, 0, 0, 0, 0, 0}, xB = xA;
    if (vA) xA = *(const u16x8*)(h1 + (size_t)(pkA & 0x3fffffff) * 64 + f0);
    if (vB) xB = *(const u16x8*)(h1 + (size_t)(pkB & 0x3fffffff) * 64 + f0);
    float rA = (vA && (pkA >> 30)) ? 1.f : 0.f;
    float sA = vA ? 1.f : 0.f;
    float rB = (vB && (pkB >> 30)) ? 1.f : 0.f;
    float sB = vB ? 1.f : 0.f;
    c0 += (sA - rA) + (sB - rB);
    c1 += rA + rB;
#pragma unroll
    for (int j = 0; j < 8; ++j) {
      float fA = bf2f(xA[j]), fB = bf2f(xB[j]);
      a0[j] += (sA - rA) * fA + (sB - rB) * fB;
      a1[j] += rA * fA + rB * fB;
    }
  }

#pragma unroll
  for (int msk = 8; msk <= 32; msk <<= 1) {
#pragma unroll
    for (int j = 0; j < 8; ++j) {
      a0[j] += __shfl_xor(a0[j], msk);
      a1[j] += __shfl_xor(a1[j], msk);
    }
    c0 += __shfl_xor(c0, msk);
    c1 += __shfl_xor(c1, msk);
  }

  float inv0 = 1.f / fmaxf(c0, 1.f);
  float inv1 = 1.f / fmaxf(c1, 1.f);
  u16x8 hv = *(const u16x8*)(h1 + (size_t)n * 64 + f0);
  float4 wA = *(const float4*)(w2g + f0);
  float4 wB = *(const float4*)(w2g + f0 + 4);
  float4 uA = *(const float4*)(w2g + 64 + f0);
  float4 uB = *(const float4*)(w2g + 64 + f0 + 4);
  float4 vA = *(const float4*)(w2g + 128 + f0);
  float4 vB = *(const float4*)(w2g + 128 + f0 + 4);
  float wv[8] = {wA.x, wA.y, wA.z, wA.w, wB.x, wB.y, wB.z, wB.w};
  float uv[8] = {uA.x, uA.y, uA.z, uA.w, uB.x, uB.y, uB.z, uB.w};
  float vv8[8] = {vA.x, vA.y, vA.z, vA.w, vB.x, vB.y, vB.z, vB.w};
  float dot = 0.f;
#pragma unroll
  for (int j = 0; j < 8; ++j) {
    dot = fmaf(bf2f(hv[j]), wv[j], dot);
    dot = fmaf(a0[j] * inv0, uv[j], dot);
    dot = fmaf(a1[j] * inv1, vv8[j], dot);
  }
  dot += __shfl_xor(dot, 1);
  dot += __shfl_xor(dot, 2);
  dot += __shfl_xor(dot, 4);
  if (lane == 0) hval[n] = dot + *cb;
}

// ---------------- GAT (CSR, wave per node, lane per edge) ----------------
__device__ __forceinline__ float leaky(float x) { return x > 0.f ? x : 0.2f * x; }

__global__ __launch_bounds__(256) void gat_csr(const int* __restrict__ rowptr,
                                               const int* __restrict__ partial,
                                               const int* __restrict__ srcpk,
                                               const float* __restrict__ hval,
                                               const float* __restrict__ as_,
                                               const float* __restrict__ ad_,
                                               const float* __restrict__ gb,
                                               float* __restrict__ out, int N) {
  int n = blockIdx.x * 4 + (threadIdx.x >> 6);
  if (n >= N) return;
  const int lane = threadIdx.x & 63;
  float as = *as_, ad = *ad_;
  float hv = hval[n];
  float adn = hv * ad;
  float eself = leaky(hv * as + adn);
  const int beg = rowptr[n] + partial[n >> 10];
  const int end = rowptr[n + 1] + partial[(n + 1) >> 10];
  int deg = end - beg;
  float m, den, acc;
  if (deg <= 64) {
    bool valid = lane < deg;
    float hs = 0.f;
    if (valid) hs = hval[srcpk[beg + lane] & 0x3fffffff];
    float e = valid ? leaky(hs * as + adn) : -3.4e38f;
    m = fmaxf(e, eself);
#pragma unroll
    for (int o = 32; o > 0; o >>= 1) m = fmaxf(m, __shfl_xor(m, o));
    float ex = valid ? expf(e - m) : 0.f;
    den = ex;
    acc = ex * hs;
#pragma unroll
    for (int o = 32; o > 0; o >>= 1) {
      den += __shfl_xor(den, o);
      acc += __shfl_xor(acc, o);
    }
  } else {
    m = eself;
    for (int i = beg + lane; i < end; i += 64)
      m = fmaxf(m, leaky(hval[srcpk[i] & 0x3fffffff] * as + adn));
#pragma unroll
    for (int o = 32; o > 0; o >>= 1) m = fmaxf(m, __shfl_xor(m, o));
    float dl = 0.f, al = 0.f;
    for (int i = beg + lane; i < end; i += 64) {
      float hs = hval[srcpk[i] & 0x3fffffff];
      float ex = expf(leaky(hs * as + adn) - m);
      dl += ex;
      al += ex * hs;
    }
    den = dl;
    acc = al;
#pragma unroll
    for (int o = 32; o > 0; o >>= 1) {
      den += __shfl_xor(den, o);
      acc += __shfl_xor(acc, o);
    }
  }
  float es = expf(eself - m);
  den += es;
  acc += es * hv;
  if (lane == 0) out[n] = acc / den + *gb;
}

// ---------------- launch ----------------
extern "C" void kernel_launch(void* const* d_in, const int* in_sizes, int n_in,
                              void* d_out, int out_size, void* d_ws, size_t ws_size,
                              hipStream_t stream) {
  const float* x      = (const float*)d_in[0];
  const int*   eidx   = (const int*)d_in[1];
  const int*   etype  = (const int*)d_in[2];
  const float* basis1 = (const float*)d_in[3];
  const float* comp1  = (const float*)d_in[4];
  const float* root1  = (const float*)d_in[5];
  const float* bias1  = (const float*)d_in[6];
  const float* basis2 = (const float*)d_in[7];
  const float* comp2  = (const float*)d_in[8];
  const float* root2  = (const float*)d_in[9];
  const float* bias2  = (const float*)d_in[10];
  const float* gat_w  = (const float*)d_in[11];
  const float* att_s  = (const float*)d_in[12];
  const float* att_d  = (const float*)d_in[13];
  const float* gat_b  = (const float*)d_in[14];

  const int N = in_sizes[0] / 512;   // 100000
  const int E = in_sizes[1] / 2;     // 1600000
  const int* src = eidx;
  const int* dst = eidx + E;

  // workspace carve-up (16B-aligned segments)
  char* p = (char*)d_ws;
  ushort* Y    = (ushort*)p; p += (size_t)N * NCOL * 2;        // 38.4 MB (bf16)
  ushort* h1   = (ushort*)p; p += (size_t)N * 64 * 2;          // 12.8 MB (bf16)
  ushort* Wpk1 = (ushort*)p; p += (size_t)512 * NCOL * 2;      // 196 KB
  float* w2g   = (float*)p;  p += 192 * 4;
  float* cb    = (float*)p;  p += 16 * 4;
  float* hval  = (float*)p;  p += (size_t)N * 4;
  int* deg     = (int*)p;    p += (size_t)N * 4;               // zeroed together
  int* fill    = (int*)p;    p += (size_t)N * 4;               //  (one kernel)
  int* rowptr  = (int*)p;    p += (size_t)(N + 16) * 4;
  int* partial = (int*)p;    p += (size_t)(SCAN_T + 16) * 4;
  int* srcpk   = (int*)p;    p += (size_t)E * 4;               // 6.4 MB
  float* out   = (float*)d_out;

  const int TB = 256;
  const int GB = (N + 63) / 64;
  const int nb = (N + 1 + SCAN_ELEMS - 1) / SCAN_ELEMS;

  // ---- CSR build (shared by both layers and GAT) ----
  zero_int<<<(2 * N + TB - 1) / TB, TB, 0, stream>>>(deg, 2 * N);  // deg + fill
  hist_deg<<<(E + TB - 1) / TB, TB, 0, stream>>>(dst, deg, E);
  scan_local<<<nb, SCAN_T, 0, stream>>>(deg, rowptr, partial, N);
  scan_partial<<<1, SCAN_T, 0, stream>>>(partial, nb);
  scatter_edges<<<(E + TB - 1) / TB, TB, 0, stream>>>(src, dst, etype, rowptr, partial,
                                                      fill, srcpk, E);

  // ---- weights: Wpk1 (thread-per-elem) + w2g/cb (wave-per-output), one dispatch ----
  build_weights<<<(512 * NCOL + 193 * 64 + TB - 1) / TB, TB, 0, stream>>>(
      basis1, comp1, root1, basis2, comp2, root2, bias2, gat_w, Wpk1, w2g, cb);

  // ---- layer 1 (K=512) ----
  gemm_mfma<512, 0><<<GB, 256, 0, stream>>>(x, Wpk1, Y, N);
  agg_layer1<<<(N + 3) / 4, TB, 0, stream>>>(Y, rowptr, partial, srcpk, bias1, h1, N);

  // ---- layer 2 folded into per-node 192-dot ----
  agg_layer2<<<(N + 3) / 4, TB, 0, stream>>>(h1, rowptr, partial, srcpk, w2g, cb, hval, N);

  // ---- GAT ----
  gat_csr<<<(N + 3) / 4, TB, 0, stream>>>(rowptr, partial, srcpk, hval, att_s, att_d, gat_b,
                                          out, N);
}

// Round 17
// 348.037 us; speedup vs baseline: 1.0755x; 1.0755x over previous
//
#include <hip/hip_runtime.h>
#include <hip/hip_bf16.h>
#include <math.h>

#define NCOL 192   // 64 root | 64 rel0 | 64 rel1
#define BB   30    // bases
#define SCAN_T 256
#define SCAN_ELEMS 1024   // per scan block (4 per thread)

typedef short bf16x8 __attribute__((ext_vector_type(8)));
typedef float f32x4  __attribute__((ext_vector_type(4)));
typedef unsigned short u16x8 __attribute__((ext_vector_type(8)));

__device__ __forceinline__ ushort f2bf(float f) {
  unsigned u = __float_as_uint(f);
  unsigned r = u + 0x7fff + ((u >> 16) & 1);   // RTNE
  return (ushort)(r >> 16);
}
__device__ __forceinline__ float bf2f(ushort u) {
  return __uint_as_float(((unsigned)u) << 16);
}

// ---------------- CSR build ----------------
__global__ void zero_int(int* __restrict__ p, int n) {
  int i = blockIdx.x * blockDim.x + threadIdx.x;
  if (i < n) p[i] = 0;
}

__global__ void hist_deg(const int* __restrict__ dst, int* __restrict__ deg, int E) {
  int e = blockIdx.x * blockDim.x + threadIdx.x;
  if (e >= E) return;
  atomicAdd(&deg[dst[e]], 1);
}

__global__ __launch_bounds__(SCAN_T) void scan_local(const int* __restrict__ deg,
                                                     int* __restrict__ rowptr,
                                                     int* __restrict__ partial, int N) {
  __shared__ int sdata[SCAN_T];
  int t = threadIdx.x;
  int base = blockIdx.x * SCAN_ELEMS + t * 4;
  int v[4], s = 0;
#pragma unroll
  for (int k = 0; k < 4; ++k) {
    v[k] = (base + k < N) ? deg[base + k] : 0;
    s += v[k];
  }
  sdata[t] = s;
  __syncthreads();
  for (int off = 1; off < SCAN_T; off <<= 1) {
    int add = (t >= off) ? sdata[t - off] : 0;
    __syncthreads();
    sdata[t] += add;
    __syncthreads();
  }
  int run = sdata[t] - s;
  if (t == SCAN_T - 1) partial[blockIdx.x] = sdata[t];
#pragma unroll
  for (int k = 0; k < 4; ++k) {
    if (base + k <= N) rowptr[base + k] = run;   // includes index N
    run += v[k];
  }
}

__global__ __launch_bounds__(SCAN_T) void scan_partial(int* __restrict__ partial, int nb) {
  __shared__ int sdata[SCAN_T];
  int t = threadIdx.x;
  int v = (t < nb) ? partial[t] : 0;
  sdata[t] = v;
  __syncthreads();
  for (int off = 1; off < SCAN_T; off <<= 1) {
    int add = (t >= off) ? sdata[t - off] : 0;
    __syncthreads();
    sdata[t] += add;
    __syncthreads();
  }
  if (t < nb) partial[t] = sdata[t] - v;
  if (t == nb - 1) partial[nb] = sdata[t];
}

__global__ void scatter_edges(const int* __restrict__ src, const int* __restrict__ dst,
                              const int* __restrict__ et, const int* __restrict__ rowptr,
                              const int* __restrict__ partial,
                              int* __restrict__ fill, int* __restrict__ srcpk, int E) {
  int e = blockIdx.x * blockDim.x + threadIdx.x;
  if (e >= E) return;
  int d = dst[e];
  int pos = rowptr[d] + partial[d >> 10] + atomicAdd(&fill[d], 1);
  srcpk[pos] = src[e] | (et[e] << 30);
}

// ---------------- weights ----------------
// Wpk1: chunked + XOR-preswizzled: k -> chunk=k>>6, kg=(k>>3)&7, elem=k&7;
// slot=(kg*192+j)^kg; Wpk[chunk*12288 + slot*8 + elem].
// w2g/cb: WAVE per output c, lanes coalesced over o, shfl reduce.
__global__ void build_weights(const float* __restrict__ basis1, const float* __restrict__ comp1,
                              const float* __restrict__ root1,
                              const float* __restrict__ basis2, const float* __restrict__ comp2,
                              const float* __restrict__ root2,
                              const float* __restrict__ bias2, const float* __restrict__ gw,
                              ushort* __restrict__ Wpk1, float* __restrict__ w2g,
                              float* __restrict__ cb) {
  int idx = blockIdx.x * blockDim.x + threadIdx.x;
  if (idx < 512 * NCOL) {
    int k = idx / NCOL, j = idx - k * NCOL;
    float v;
    if (j < 64) {
      v = root1[k * 64 + j];
    } else {
      int r = (j >> 6) - 1, o = j & 63;
      float s = 0.f;
#pragma unroll
      for (int b = 0; b < BB; ++b)
        s = fmaf(comp1[r * BB + b], basis1[((size_t)b * 512 + k) * 64 + o], s);
      v = s;
    }
    int chunk = k >> 6, kg = (k >> 3) & 7, elem = k & 7;
    int slot = (kg * NCOL + j) ^ kg;
    Wpk1[(size_t)chunk * 12288 + slot * 8 + elem] = f2bf(v);
    return;
  }
  int widx = idx - 512 * NCOL;
  int c = widx >> 6;            // wave-aligned (base is 256-divisible)
  int o = widx & 63;
  if (c < 192) {
    int k = c & 63, part = c >> 6;
    float s;
    if (part == 0) {
      s = root2[k * 64 + o] * gw[o];
    } else {
      int r = part - 1;
      float t = 0.f;
#pragma unroll
      for (int b = 0; b < BB; ++b)
        t = fmaf(comp2[r * BB + b], basis2[((size_t)b * 64 + k) * 64 + o], t);
      s = t * gw[o];
    }
#pragma unroll
    for (int off = 32; off > 0; off >>= 1) s += __shfl_xor(s, off);
    if (o == 0) w2g[c] = s;
  } else if (c == 192) {
    float s = bias2[o] * gw[o];
#pragma unroll
    for (int off = 32; off > 0; off >>= 1) s += __shfl_xor(s, off);
    if (o == 0) *cb = s;
  }
}

// ---------------- GEMM: W -> LDS via async global_load_lds, A direct from global ----
template <int K, int BF16IN>
__global__ __launch_bounds__(256, 3) void gemm_mfma(const void* __restrict__ Xv,
                                                    const ushort* __restrict__ Wpk,
                                                    ushort* __restrict__ Y, int N) {
  constexpr int NC = K / 64;             // BK=64 chunks
  constexpr int NB = (NC > 1) ? 2 : 1;   // LDS buffers
  __shared__ ushort Ws[NB * 12288];      // 24.6 KB per buffer

  const int tid  = threadIdx.x;
  const int wid  = tid >> 6;
  const int lane = tid & 63;
  const int lrow = lane & 15;
  const int lhi  = lane >> 4;
  const int row0 = blockIdx.x * 64 + wid * 16;

  int lr = row0 + lrow;
  if (lr >= N) lr = N - 1;               // clamp A loads; C stores guarded
  const float*  Xf = (const float*)Xv  + (size_t)lr * K;
  const ushort* Xh = (const ushort*)Xv + (size_t)lr * K;

#define GLOAD_W(c, buf)                                                        \
  { const ushort* gsrc = Wpk + (size_t)(c) * 12288 + wid * 3072 + lane * 8;    \
    ushort* ldst = Ws + (size_t)(buf) * 12288 + wid * 3072;                    \
    _Pragma("unroll") for (int i = 0; i < 6; ++i)                              \
      __builtin_amdgcn_global_load_lds(                                        \
          (const __attribute__((address_space(1))) unsigned int*)(gsrc + i * 512), \
          (__attribute__((address_space(3))) unsigned int*)(ldst + i * 512),   \
          16, 0, 0); }

  float4 pa[2][4];
  u16x8  ph[2][2];
#define LOAD_A(c, slot)                                                       \
  if constexpr (BF16IN) {                                                     \
    ph[slot][0] = ((const u16x8*)Xh)[(c) * 8 + lhi];                          \
    ph[slot][1] = ((const u16x8*)Xh)[(c) * 8 + 4 + lhi];                      \
  } else {                                                                    \
    _Pragma("unroll") for (int q = 0; q < 4; ++q)                             \
      pa[slot][q] = ((const float4*)Xf)[(c) * 16 + (q >> 1) * 8 + lhi * 2 + (q & 1)]; \
  }
#define MAT_A(slot, tt, areg)                                                 \
  if constexpr (BF16IN) {                                                     \
    areg = (bf16x8)ph[slot][tt];                                              \
  } else {                                                                    \
    float4 v0 = pa[slot][(tt) * 2], v1 = pa[slot][(tt) * 2 + 1];              \
    areg[0] = (short)f2bf(v0.x); areg[1] = (short)f2bf(v0.y);                 \
    areg[2] = (short)f2bf(v0.z); areg[3] = (short)f2bf(v0.w);                 \
    areg[4] = (short)f2bf(v1.x); areg[5] = (short)f2bf(v1.y);                 \
    areg[6] = (short)f2bf(v1.z); areg[7] = (short)f2bf(v1.w);                 \
  }
#define COMP(buf, tt, areg)                                                   \
  { const int kg = (tt) * 4 + lhi;                                            \
    const ushort* ls = Ws + (size_t)(buf) * 12288;                            \
    _Pragma("unroll") for (int h = 0; h < 2; ++h) {                           \
      bf16x8 b[6];                                                            \
      _Pragma("unroll") for (int q = 0; q < 6; ++q) {                         \
        int slot = (kg * NCOL + (h * 6 + q) * 16 + lrow) ^ (kg & 7);          \
        b[q] = *(const bf16x8*)(ls + slot * 8);                               \
      }                                                                       \
      _Pragma("unroll") for (int q = 0; q < 6; ++q)                           \
        acc[h * 6 + q] = __builtin_amdgcn_mfma_f32_16x16x32_bf16(areg, b[q],  \
                                                     acc[h * 6 + q], 0, 0, 0); \
    } }

  GLOAD_W(0, 0)
  LOAD_A(0, 0)
  if constexpr (NC > 1) { LOAD_A(1, 1) }
  __syncthreads();

  f32x4 acc[12];
#pragma unroll
  for (int cc = 0; cc < 12; ++cc) acc[cc] = (f32x4){0.f, 0.f, 0.f, 0.f};

#pragma unroll
  for (int c = 0; c < NC; ++c) {
    if (c + 1 < NC) { GLOAD_W(c + 1, (c + 1) & 1) }
    bf16x8 a0, a1;
    MAT_A(c & 1, 0, a0)
    MAT_A(c & 1, 1, a1)
    if (c + 2 < NC) { LOAD_A(c + 2, c & 1) }
    COMP(NB > 1 ? (c & 1) : 0, 0, a0)
    COMP(NB > 1 ? (c & 1) : 0, 1, a1)
    if (c + 1 < NC) {
      __syncthreads();   // one barrier per chunk: drains DMA + readers
    }
  }
#undef GLOAD_W
#undef LOAD_A
#undef MAT_A
#undef COMP

  // C/D: col = lane&15, row = (lane>>4)*4 + reg   [m89]
#pragma unroll
  for (int cc = 0; cc < 12; ++cc) {
#pragma unroll
    for (int j = 0; j < 4; ++j) {
      int r = row0 + lhi * 4 + j;
      if (r < N) Y[(size_t)r * NCOL + cc * 16 + lrow] = f2bf(acc[cc][j]);
    }
  }
}

// ---------------- layer-1 aggregation + layer-2 pre-dots ----------------
// Wave per node; 8 groups x 8 lanes. Epilogue additionally computes
// svf[2n+0]=h1[n].u, svf[2n+1]=h1[n].v, hs[n]=h1[n].w  (u,v,w = w2g parts),
// so layer-2's edge gather needs only 4B/edge instead of 128B.
__global__ __launch_bounds__(256) void agg_layer1(const ushort* __restrict__ Y,
                                                  const int* __restrict__ rowptr,
                                                  const int* __restrict__ partial,
                                                  const int* __restrict__ srcpk,
                                                  const float* __restrict__ bias,
                                                  const float* __restrict__ w2g,
                                                  ushort* __restrict__ h1,
                                                  float* __restrict__ svf,
                                                  float* __restrict__ hs, int N) {
  int n = blockIdx.x * 4 + (threadIdx.x >> 6);
  if (n >= N) return;
  const int lane = threadIdx.x & 63;
  const int g    = lane >> 3;
  const int f0   = (lane & 7) * 8;

  float a0[8], a1[8];
#pragma unroll
  for (int j = 0; j < 8; ++j) { a0[j] = 0.f; a1[j] = 0.f; }
  float c0 = 0.f, c1 = 0.f;

  const int beg = rowptr[n] + partial[n >> 10];
  const int end = rowptr[n + 1] + partial[(n + 1) >> 10];
  for (int i = beg; i < end; i += 16) {
    int eA = i + g, eB = i + 8 + g;
    bool vA = eA < end, vB = eB < end;
    int pkA = 0, pkB = 0;
    if (vA) pkA = srcpk[eA];
    if (vB) pkB = srcpk[eB];
    u16x8 xA = (u16x8){0, 0, 0, 0, 0, 0, 0, 0}, xB = xA;
    if (vA) xA = *(const u16x8*)(Y + (size_t)(pkA & 0x3fffffff) * NCOL + 64 +
                                 ((pkA >> 30) << 6) + f0);
    if (vB) xB = *(const u16x8*)(Y + (size_t)(pkB & 0x3fffffff) * NCOL + 64 +
                                 ((pkB >> 30) << 6) + f0);
    float rA = (vA && (pkA >> 30)) ? 1.f : 0.f;
    float sA = vA ? 1.f : 0.f;
    float rB = (vB && (pkB >> 30)) ? 1.f : 0.f;
    float sB = vB ? 1.f : 0.f;
    c0 += (sA - rA) + (sB - rB);
    c1 += rA + rB;
#pragma unroll
    for (int j = 0; j < 8; ++j) {
      float fA = bf2f(xA[j]), fB = bf2f(xB[j]);
      a0[j] += (sA - rA) * fA + (sB - rB) * fB;
      a1[j] += rA * fA + rB * fB;
    }
  }

#pragma unroll
  for (int msk = 8; msk <= 32; msk <<= 1) {
#pragma unroll
    for (int j = 0; j < 8; ++j) {
      a0[j] += __shfl_xor(a0[j], msk);
      a1[j] += __shfl_xor(a1[j], msk);
    }
    c0 += __shfl_xor(c0, msk);
    c1 += __shfl_xor(c1, msk);
  }

  if (g == 0) {  // lanes 0..7: feature slice f0 = 8*(lane&7)
    float inv0 = 1.f / fmaxf(c0, 1.f);
    float inv1 = 1.f / fmaxf(c1, 1.f);
    u16x8 rv = *(const u16x8*)(Y + (size_t)n * NCOL + f0);
    float4 bA = *(const float4*)(bias + f0);
    float4 bB = *(const float4*)(bias + f0 + 4);
    float bb[8] = {bA.x, bA.y, bA.z, bA.w, bB.x, bB.y, bB.z, bB.w};
    float res[8];
    u16x8 o;
#pragma unroll
    for (int j = 0; j < 8; ++j) {
      float v = bf2f(rv[j]) + bb[j] + a0[j] * inv0 + a1[j] * inv1;
      res[j] = fmaxf(v, 0.f);
      o[j] = f2bf(res[j]);
    }
    *(u16x8*)(h1 + (size_t)n * 64 + f0) = o;

    // layer-2 pre-dots on the bf16-rounded h1 (matches what agg2 would read)
    float4 wA = *(const float4*)(w2g + f0);
    float4 wB = *(const float4*)(w2g + f0 + 4);
    float4 uA = *(const float4*)(w2g + 64 + f0);
    float4 uB = *(const float4*)(w2g + 64 + f0 + 4);
    float4 vA4 = *(const float4*)(w2g + 128 + f0);
    float4 vB4 = *(const float4*)(w2g + 128 + f0 + 4);
    float wv[8] = {wA.x, wA.y, wA.z, wA.w, wB.x, wB.y, wB.z, wB.w};
    float uv[8] = {uA.x, uA.y, uA.z, uA.w, uB.x, uB.y, uB.z, uB.w};
    float vv[8] = {vA4.x, vA4.y, vA4.z, vA4.w, vB4.x, vB4.y, vB4.z, vB4.w};
    float dw = 0.f, du = 0.f, dv = 0.f;
#pragma unroll
    for (int j = 0; j < 8; ++j) {
      float h = bf2f(o[j]);
      dw = fmaf(h, wv[j], dw);
      du = fmaf(h, uv[j], du);
      dv = fmaf(h, vv[j], dv);
    }
#pragma unroll
    for (int msk = 1; msk <= 4; msk <<= 1) {
      dw += __shfl_xor(dw, msk);
      du += __shfl_xor(du, msk);
      dv += __shfl_xor(dv, msk);
    }
    if (lane == 0) {
      svf[2 * (size_t)n]     = du;   // rel-0 contribution
      svf[2 * (size_t)n + 1] = dv;   // rel-1 contribution
      hs[n] = dw;                    // self/root contribution
    }
  }
}

// ---------------- layer-2: scalar segment means over pre-dots ----------------
// hval[n] = hs[n] + mean0(svf[2*src]) + mean1(svf[2*src+1]) + cb.
// Wave per node, lane per edge; svf is 800KB (L2-resident) -> 4B gather/edge.
__global__ __launch_bounds__(256) void agg2_scalar(const int* __restrict__ rowptr,
                                                   const int* __restrict__ partial,
                                                   const int* __restrict__ srcpk,
                                                   const float* __restrict__ svf,
                                                   const float* __restrict__ hs,
                                                   const float* __restrict__ cb,
                                                   float* __restrict__ hval, int N) {
  int n = blockIdx.x * 4 + (threadIdx.x >> 6);
  if (n >= N) return;
  const int lane = threadIdx.x & 63;
  const int beg = rowptr[n] + partial[n >> 10];
  const int end = rowptr[n + 1] + partial[(n + 1) >> 10];
  int deg = end - beg;
  float s0 = 0.f, s1 = 0.f, c0 = 0.f, c1 = 0.f;
  if (deg <= 64) {
    if (lane < deg) {
      int pk = srcpk[beg + lane];
      int r = pk >> 30;
      float s = svf[2 * (size_t)(pk & 0x3fffffff) + r];
      if (r) { s1 = s; c1 = 1.f; } else { s0 = s; c0 = 1.f; }
    }
  } else {
    for (int i = beg + lane; i < end; i += 64) {
      int pk = srcpk[i];
      int r = pk >> 30;
      float s = svf[2 * (size_t)(pk & 0x3fffffff) + r];
      if (r) { s1 += s; c1 += 1.f; } else { s0 += s; c0 += 1.f; }
    }
  }
#pragma unroll
  for (int o = 32; o > 0; o >>= 1) {
    s0 += __shfl_xor(s0, o);
    s1 += __shfl_xor(s1, o);
    c0 += __shfl_xor(c0, o);
    c1 += __shfl_xor(c1, o);
  }
  if (lane == 0)
    hval[n] = hs[n] + s0 / fmaxf(c0, 1.f) + s1 / fmaxf(c1, 1.f) + *cb;
}

// ---------------- GAT (CSR, wave per node, lane per edge) ----------------
__device__ __forceinline__ float leaky(float x) { return x > 0.f ? x : 0.2f * x; }

__global__ __launch_bounds__(256) void gat_csr(const int* __restrict__ rowptr,
                                               const int* __restrict__ partial,
                                               const int* __restrict__ srcpk,
                                               const float* __restrict__ hval,
                                               const float* __restrict__ as_,
                                               const float* __restrict__ ad_,
                                               const float* __restrict__ gb,
                                               float* __restrict__ out, int N) {
  int n = blockIdx.x * 4 + (threadIdx.x >> 6);
  if (n >= N) return;
  const int lane = threadIdx.x & 63;
  float as = *as_, ad = *ad_;
  float hv = hval[n];
  float adn = hv * ad;
  float eself = leaky(hv * as + adn);
  const int beg = rowptr[n] + partial[n >> 10];
  const int end = rowptr[n + 1] + partial[(n + 1) >> 10];
  int deg = end - beg;
  float m, den, acc;
  if (deg <= 64) {
    bool valid = lane < deg;
    float hs = 0.f;
    if (valid) hs = hval[srcpk[beg + lane] & 0x3fffffff];
    float e = valid ? leaky(hs * as + adn) : -3.4e38f;
    m = fmaxf(e, eself);
#pragma unroll
    for (int o = 32; o > 0; o >>= 1) m = fmaxf(m, __shfl_xor(m, o));
    float ex = valid ? expf(e - m) : 0.f;
    den = ex;
    acc = ex * hs;
#pragma unroll
    for (int o = 32; o > 0; o >>= 1) {
      den += __shfl_xor(den, o);
      acc += __shfl_xor(acc, o);
    }
  } else {
    m = eself;
    for (int i = beg + lane; i < end; i += 64)
      m = fmaxf(m, leaky(hval[srcpk[i] & 0x3fffffff] * as + adn));
#pragma unroll
    for (int o = 32; o > 0; o >>= 1) m = fmaxf(m, __shfl_xor(m, o));
    float dl = 0.f, al = 0.f;
    for (int i = beg + lane; i < end; i += 64) {
      float hs = hval[srcpk[i] & 0x3fffffff];
      float ex = expf(leaky(hs * as + adn) - m);
      dl += ex;
      al += ex * hs;
    }
    den = dl;
    acc = al;
#pragma unroll
    for (int o = 32; o > 0; o >>= 1) {
      den += __shfl_xor(den, o);
      acc += __shfl_xor(acc, o);
    }
  }
  float es = expf(eself - m);
  den += es;
  acc += es * hv;
  if (lane == 0) out[n] = acc / den + *gb;
}

// ---------------- launch ----------------
extern "C" void kernel_launch(void* const* d_in, const int* in_sizes, int n_in,
                              void* d_out, int out_size, void* d_ws, size_t ws_size,
                              hipStream_t stream) {
  const float* x      = (const float*)d_in[0];
  const int*   eidx   = (const int*)d_in[1];
  const int*   etype  = (const int*)d_in[2];
  const float* basis1 = (const float*)d_in[3];
  const float* comp1  = (const float*)d_in[4];
  const float* root1  = (const float*)d_in[5];
  const float* bias1  = (const float*)d_in[6];
  const float* basis2 = (const float*)d_in[7];
  const float* comp2  = (const float*)d_in[8];
  const float* root2  = (const float*)d_in[9];
  const float* bias2  = (const float*)d_in[10];
  const float* gat_w  = (const float*)d_in[11];
  const float* att_s  = (const float*)d_in[12];
  const float* att_d  = (const float*)d_in[13];
  const float* gat_b  = (const float*)d_in[14];

  const int N = in_sizes[0] / 512;   // 100000
  const int E = in_sizes[1] / 2;     // 1600000
  const int* src = eidx;
  const int* dst = eidx + E;

  // workspace carve-up (16B-aligned segments)
  char* p = (char*)d_ws;
  ushort* Y    = (ushort*)p; p += (size_t)N * NCOL * 2;        // 38.4 MB (bf16)
  ushort* h1   = (ushort*)p; p += (size_t)N * 64 * 2;          // 12.8 MB (bf16)
  ushort* Wpk1 = (ushort*)p; p += (size_t)512 * NCOL * 2;      // 196 KB
  float* w2g   = (float*)p;  p += 192 * 4;
  float* cb    = (float*)p;  p += 16 * 4;
  float* hval  = (float*)p;  p += (size_t)N * 4;
  float* svf   = (float*)p;  p += (size_t)N * 2 * 4;           // 800 KB pre-dots
  float* hs    = (float*)p;  p += (size_t)N * 4;               // 400 KB
  int* deg     = (int*)p;    p += (size_t)N * 4;               // zeroed together
  int* fill    = (int*)p;    p += (size_t)N * 4;               //  (one kernel)
  int* rowptr  = (int*)p;    p += (size_t)(N + 16) * 4;
  int* partial = (int*)p;    p += (size_t)(SCAN_T + 16) * 4;
  int* srcpk   = (int*)p;    p += (size_t)E * 4;               // 6.4 MB
  float* out   = (float*)d_out;

  const int TB = 256;
  const int GB = (N + 63) / 64;
  const int nb = (N + 1 + SCAN_ELEMS - 1) / SCAN_ELEMS;

  // ---- CSR build (shared by both layers and GAT) ----
  zero_int<<<(2 * N + TB - 1) / TB, TB, 0, stream>>>(deg, 2 * N);  // deg + fill
  hist_deg<<<(E + TB - 1) / TB, TB, 0, stream>>>(dst, deg, E);
  scan_local<<<nb, SCAN_T, 0, stream>>>(deg, rowptr, partial, N);
  scan_partial<<<1, SCAN_T, 0, stream>>>(partial, nb);
  scatter_edges<<<(E + TB - 1) / TB, TB, 0, stream>>>(src, dst, etype, rowptr, partial,
                                                      fill, srcpk, E);

  // ---- weights: Wpk1 (thread-per-elem) + w2g/cb (wave-per-output), one dispatch ----
  build_weights<<<(512 * NCOL + 193 * 64 + TB - 1) / TB, TB, 0, stream>>>(
      basis1, comp1, root1, basis2, comp2, root2, bias2, gat_w, Wpk1, w2g, cb);

  // ---- layer 1 (K=512) + layer-2 pre-dots ----
  gemm_mfma<512, 0><<<GB, 256, 0, stream>>>(x, Wpk1, Y, N);
  agg_layer1<<<(N + 3) / 4, TB, 0, stream>>>(Y, rowptr, partial, srcpk, bias1, w2g,
                                             h1, svf, hs, N);

  // ---- layer 2: scalar segment means ----
  agg2_scalar<<<(N + 3) / 4, TB, 0, stream>>>(rowptr, partial, srcpk, svf, hs, cb, hval, N);

  // ---- GAT ----
  gat_csr<<<(N + 3) / 4, TB, 0, stream>>>(rowptr, partial, srcpk, hval, att_s, att_d, gat_b,
                                          out, N);
}